// Round 12
// baseline (116.911 us; speedup 1.0000x reference)
//
#include <hip/hip_runtime.h>
#include <math.h>

// HAKE scoring for MI355X — round 12: 3-kernel pipeline, coalesce everything.
// R10/R11 lesson: inner VALU cut 2x moved nothing -> wall isn't inner pipes;
// unmodeled term = prologue VMEM gathers (B-frag/A-frag/SC scatter loads,
// ~6-8us/CU TA time) + MFMA block forcing extra barrier in all 1250 blocks.
// Now: prep writes X transposed [d][b] (coalesced main loads); rgemm = own
// 313-block kernel (R5-verified structure, A from ws) writing R+S0 to ws;
// main = pure phase kernel, all loads/stores coalesced, 2 barriers,
// 33.8KB LDS, lb(512,8) -> 32 waves/CU.

#define D_   256
#define N_   20000
#define NT   16
#define NBLK (N_ / NT)      // 1250

// rev units for sin(x/2): 1/(4*EMB_RANGE)
#define K2S 4.571428571428571f

// ws layout (bytes)
#define WS_A1 0          // 32x256 bf16
#define WS_A2 16384      // 32x256 bf16
#define WS_XT 32768      // 256x32 u32 (packed half2 (-cos,sin)), [d][b]
#define WS_S0 65536      // 32 f32
#define WS_R  65792      // 32x20000 f32

typedef short short8 __attribute__((ext_vector_type(8)));
typedef float f32x4  __attribute__((ext_vector_type(4)));
typedef _Float16 half2_t __attribute__((ext_vector_type(2)));

union PKH { unsigned u; half2_t h; };

__device__ __forceinline__ float sinrev_(float x) { return __builtin_amdgcn_sinf(x); }
__device__ __forceinline__ float cosrev_(float x) { return __builtin_amdgcn_cosf(x); }

__device__ __forceinline__ unsigned short bf16r(float x) {
    union { float f; unsigned u; } v; v.f = x;
    return (unsigned short)((v.u + 0x7FFFu + ((v.u >> 16) & 1u)) >> 16);
}

__device__ __forceinline__ short8 pack8(float4 a, float4 b, bool sq) {
    float v[8] = {a.x, a.y, a.z, a.w, b.x, b.y, b.z, b.w};
    short8 r;
#pragma unroll
    for (int i = 0; i < 8; ++i) { float x = sq ? v[i] * v[i] : v[i]; r[i] = (short)bf16r(x); }
    return r;
}

// ---------------------------------------------------------------------------
// K0: per-(b,d) precompute. 32 blocks x 256 thr.
// A1=cc^2, A2=-2mh'cc (bf16, [b][d]); XT = packed half2 (-cos,sin) [d][b];
// S0[b] = sum mh'^2.
// ---------------------------------------------------------------------------
__global__ __launch_bounds__(256)
void hake_prep(const int* __restrict__ e1, const int* __restrict__ rel,
               const float* __restrict__ emb_e, const float* __restrict__ emb_rel,
               char* __restrict__ ws)
{
    __shared__ float sp[4];
    const int b = blockIdx.x, d = threadIdx.x;
    const int he = e1[b], hr = rel[b];
    const float ph = emb_e[(size_t)he * 512 + d];
    const float mh = emb_e[(size_t)he * 512 + 256 + d];
    const float pr = emb_rel[(size_t)hr * 768 + d];
    const float mr = emb_rel[(size_t)hr * 768 + 256 + d];
    const float bi = emb_rel[(size_t)hr * 768 + 512 + d];

    const float a = (ph + pr) * K2S;
    PKH x;
    x.h.x = (_Float16)(-cosrev_(a));
    x.h.y = (_Float16)(sinrev_(a));
    ((unsigned*)(ws + WS_XT))[d * 32 + b] = x.u;   // transposed for coalesced main loads

    const float mra = fabsf(mr);
    float bic = fminf(bi, 1.0f);
    bic = (bic < -mra) ? -mra : bic;
    const float cc  = 1.0f - bic;
    const float mhp = mh * (mra + bic);
    ((short*)(ws + WS_A1))[b * 256 + d] = (short)bf16r(cc * cc);
    ((short*)(ws + WS_A2))[b * 256 + d] = (short)bf16r(-2.0f * mhp * cc);

    float s0 = mhp * mhp;
#pragma unroll
    for (int o = 1; o < 64; o <<= 1) s0 += __shfl_xor(s0, o, 64);
    if ((threadIdx.x & 63) == 0) sp[threadIdx.x >> 6] = s0;
    __syncthreads();
    if (threadIdx.x == 0)
        ((float*)(ws + WS_S0))[b] = sp[0] + sp[1] + sp[2] + sp[3];
}

// ---------------------------------------------------------------------------
// K1: r-term GEMM (R5-verified structure, A from ws). 313 blocks x 256 thr.
// Wave w -> 16-col tile. R[b,n] = S0_b + sum cc^2 mt^2 - 2 sum mh'cc mt.
// ---------------------------------------------------------------------------
__global__ __launch_bounds__(256)
void hake_rgemm(const float* __restrict__ emb_e, char* __restrict__ ws)
{
    const int t = threadIdx.x;
    const int w = t >> 6, l = t & 63;
    const int n0 = blockIdx.x * 64 + w * 16;
    if (n0 >= N_) return;                 // wave-uniform guard

    const short* A1w = (const short*)(ws + WS_A1);
    const short* A2w = (const short*)(ws + WS_A2);
    const float* S0w = (const float*)(ws + WS_S0);
    float*       Rw  = (float*)(ws + WS_R);

    const int fr   = l & 15;
    const int koff = (l >> 4) * 8;
    const float* mtp = emb_e + (size_t)(n0 + fr) * (2 * D_) + D_;

    f32x4 acc0 = {0.f, 0.f, 0.f, 0.f};
    f32x4 acc1 = {0.f, 0.f, 0.f, 0.f};
#pragma unroll
    for (int ch = 0; ch < 8; ++ch) {
        const int d = ch * 32 + koff;
        float4 va = *(const float4*)(mtp + d);
        float4 vb = *(const float4*)(mtp + d + 4);
        short8 b2f = pack8(va, vb, false);
        short8 b1f = pack8(va, vb, true);
        short8 a1_0 = *(const short8*)(A1w + fr * 256 + d);
        short8 a2_0 = *(const short8*)(A2w + fr * 256 + d);
        short8 a1_1 = *(const short8*)(A1w + (16 + fr) * 256 + d);
        short8 a2_1 = *(const short8*)(A2w + (16 + fr) * 256 + d);
        acc0 = __builtin_amdgcn_mfma_f32_16x16x32_bf16(a1_0, b1f, acc0, 0, 0, 0);
        acc0 = __builtin_amdgcn_mfma_f32_16x16x32_bf16(a2_0, b2f, acc0, 0, 0, 0);
        acc1 = __builtin_amdgcn_mfma_f32_16x16x32_bf16(a1_1, b1f, acc1, 0, 0, 0);
        acc1 = __builtin_amdgcn_mfma_f32_16x16x32_bf16(a2_1, b2f, acc1, 0, 0, 0);
    }

    // C/D map (verified): col = lane&15 (n), row = (lane>>4)*4 + reg (b)
#pragma unroll
    for (int r = 0; r < 4; ++r) {
        const int row = (l >> 4) * 4 + r;
        Rw[(size_t)row * N_ + n0 + fr]        = acc0[r] + S0w[row];
        Rw[(size_t)(16 + row) * N_ + n0 + fr] = acc1[r] + S0w[16 + row];
    }
}

// ---------------------------------------------------------------------------
// K2: phase + finalize. 1250 blocks x 512 thr, lb(512,8) -> 32 waves/CU.
// All global traffic coalesced. LDS: Pb 16KB + redf 17.4KB. 2 barriers.
// ---------------------------------------------------------------------------
__global__ __launch_bounds__(512, 8)
void hake_main(const float* __restrict__ emb_e,
               const char* __restrict__ ws,
               const float* __restrict__ pw_p, const float* __restrict__ mw_p,
               float* __restrict__ out)
{
    __shared__ unsigned Pb[NT * 256];     // 16 KB packed (sb,cb) half2
    __shared__ float redf[8 * 32 * 17];   // 17.4 KB per-wave phase partials

    const int t   = threadIdx.x;
    const int l   = t & 63;
    const int w   = t >> 6;       // wave 0..7
    const int b   = t & 31;
    const int g   = t >> 5;       // d-group 0..15
    const int dlo = g * 16;
    const int n0  = blockIdx.x * NT;

    const unsigned* XTw = (const unsigned*)(ws + WS_XT);
    const float*    Rw  = (const float*)(ws + WS_R);

    // ---- finalize-role mapping (coalesced): fn = t&15, fb = t>>4 -----------
    const int fn = t & 15, fb = t >> 4;

    // ---- early loads (all coalesced) ---------------------------------------
    float rprefetch = Rw[(size_t)fb * N_ + n0 + fn];

    const float* prow0 = emb_e + (size_t)(n0 + w * 2) * (2 * D_);
    const float* prow1 = emb_e + (size_t)(n0 + w * 2 + 1) * (2 * D_);
    float2 lp00 = *(const float2*)(prow0 + 2 * l);
    float2 lp01 = *(const float2*)(prow0 + 128 + 2 * l);
    float2 lp10 = *(const float2*)(prow1 + 2 * l);
    float2 lp11 = *(const float2*)(prow1 + 128 + 2 * l);

    half2_t Xr[16];
#pragma unroll
    for (int i = 0; i < 16; ++i)
        Xr[i] = __builtin_bit_cast(half2_t, XTw[(dlo + i) * 32 + b]);

    // ---- stage Pb: W = (sin, cos) packed half2 -----------------------------
    {
        PKH w0, w1;
        float v0, v1;
        v0 = lp00.x * K2S; v1 = lp00.y * K2S;
        w0.h.x = (_Float16)sinrev_(v0); w0.h.y = (_Float16)cosrev_(v0);
        w1.h.x = (_Float16)sinrev_(v1); w1.h.y = (_Float16)cosrev_(v1);
        *(uint2*)(&Pb[(w * 2) * 256 + 2 * l]) = make_uint2(w0.u, w1.u);
        v0 = lp01.x * K2S; v1 = lp01.y * K2S;
        w0.h.x = (_Float16)sinrev_(v0); w0.h.y = (_Float16)cosrev_(v0);
        w1.h.x = (_Float16)sinrev_(v1); w1.h.y = (_Float16)cosrev_(v1);
        *(uint2*)(&Pb[(w * 2) * 256 + 128 + 2 * l]) = make_uint2(w0.u, w1.u);
        v0 = lp10.x * K2S; v1 = lp10.y * K2S;
        w0.h.x = (_Float16)sinrev_(v0); w0.h.y = (_Float16)cosrev_(v0);
        w1.h.x = (_Float16)sinrev_(v1); w1.h.y = (_Float16)cosrev_(v1);
        *(uint2*)(&Pb[(w * 2 + 1) * 256 + 2 * l]) = make_uint2(w0.u, w1.u);
        v0 = lp11.x * K2S; v1 = lp11.y * K2S;
        w0.h.x = (_Float16)sinrev_(v0); w0.h.y = (_Float16)cosrev_(v0);
        w1.h.x = (_Float16)sinrev_(v1); w1.h.y = (_Float16)cosrev_(v1);
        *(uint2*)(&Pb[(w * 2 + 1) * 256 + 128 + 2 * l]) = make_uint2(w0.u, w1.u);
    }
    __syncthreads();                                    // b1: Pb ready

    // ---- phase accumulate: dot2 + abs-add ----------------------------------
    float sph[NT];
#pragma unroll
    for (int j = 0; j < NT; ++j) sph[j] = 0.0f;

#pragma unroll
    for (int q = 0; q < 4; ++q) {
        const half2_t x0 = Xr[q * 4 + 0];
        const half2_t x1 = Xr[q * 4 + 1];
        const half2_t x2 = Xr[q * 4 + 2];
        const half2_t x3 = Xr[q * 4 + 3];
#pragma unroll
        for (int j = 0; j < NT; ++j) {
            uint4 tv = *(const uint4*)(&Pb[j * 256 + dlo + q * 4]);   // bcast
            sph[j] += fabsf(__builtin_amdgcn_fdot2(x0, __builtin_bit_cast(half2_t, tv.x), 0.0f, false));
            sph[j] += fabsf(__builtin_amdgcn_fdot2(x1, __builtin_bit_cast(half2_t, tv.y), 0.0f, false));
            sph[j] += fabsf(__builtin_amdgcn_fdot2(x2, __builtin_bit_cast(half2_t, tv.z), 0.0f, false));
            sph[j] += fabsf(__builtin_amdgcn_fdot2(x3, __builtin_bit_cast(half2_t, tv.w), 0.0f, false));
        }
    }

    // ---- reduce: half-wave combine, then per-wave -> redf ------------------
#pragma unroll
    for (int j = 0; j < NT; ++j) sph[j] += __shfl_xor(sph[j], 32, 64);
    if (l < 32) {
        // layout [w][b][j(pad17)]: lane l writes 16 j's as 4 float4
        float4* dst = (float4*)&redf[(w * 32 + l) * 17];
#pragma unroll
        for (int qq = 0; qq < 4; ++qq)
            dst[qq] = make_float4(sph[qq * 4 + 0], sph[qq * 4 + 1],
                                  sph[qq * 4 + 2], sph[qq * 4 + 3]);
    }
    __syncthreads();                                    // b2: redf ready

    // ---- finalize: thread -> (b = fb, n = n0 + fn), coalesced --------------
    {
        float pa = 0.0f;
#pragma unroll
        for (int ww = 0; ww < 8; ++ww) pa += redf[(ww * 32 + fb) * 17 + fn];
        float rfull = fmaxf(rprefetch, 0.0f);
        float z = fmaf(pa, pw_p[0], sqrtf(rfull) * mw_p[0]) - 12.0f;  // GAMMA
        out[(size_t)fb * N_ + (n0 + fn)] = 1.0f / (1.0f + __expf(z));
    }
}

extern "C" void kernel_launch(void* const* d_in, const int* in_sizes, int n_in,
                              void* d_out, int out_size, void* d_ws, size_t ws_size,
                              hipStream_t stream)
{
    // inputs: 0:g 1:e1 2:rel 3:e2_multi(unused) 4:emb_e 5:emb_rel 6:phase_w 7:mod_w
    const int*   e1      = (const int*)d_in[1];
    const int*   rel     = (const int*)d_in[2];
    const float* emb_e   = (const float*)d_in[4];
    const float* emb_rel = (const float*)d_in[5];
    const float* pw      = (const float*)d_in[6];
    const float* mw      = (const float*)d_in[7];
    float* out = (float*)d_out;

    hipLaunchKernelGGL(hake_prep, dim3(32), dim3(256), 0, stream,
                       e1, rel, emb_e, emb_rel, (char*)d_ws);
    hipLaunchKernelGGL(hake_rgemm, dim3(313), dim3(256), 0, stream,
                       emb_e, (char*)d_ws);
    hipLaunchKernelGGL(hake_main, dim3(NBLK), dim3(512), 0, stream,
                       emb_e, (const char*)d_ws, pw, mw, out);
}

// Round 13
// 114.985 us; speedup vs baseline: 1.0168x; 1.0168x over previous
//
#include <hip/hip_runtime.h>
#include <math.h>

// HAKE scoring for MI355X — round 13: R12 pipeline, spill-safe codegen.
// R12 lesson: main spilled catastrophically (VGPR_Count 32, WRITE 274MB) —
// everything-up-front live ranges blew the 64-VGPR cap of lb(512,8); the
// gather-elimination theory was never tested. Same 3-kernel structure,
// main rewritten for low peak pressure: individual Xr dword loads, scalar
// pad-17 redf writes, R loaded at finalize. Target VGPR<=60, 8 waves/SIMD.

#define D_   256
#define N_   20000
#define NT   16
#define NBLK (N_ / NT)      // 1250

// rev units for sin(x/2): 1/(4*EMB_RANGE)
#define K2S 4.571428571428571f

// ws layout (bytes)
#define WS_A1 0          // 32x256 bf16
#define WS_A2 16384      // 32x256 bf16
#define WS_XT 32768      // 256x32 u32 (packed half2 (-cos,sin)), [d][b]
#define WS_S0 65536      // 32 f32
#define WS_R  65792      // 32x20000 f32

typedef short short8 __attribute__((ext_vector_type(8)));
typedef float f32x4  __attribute__((ext_vector_type(4)));
typedef _Float16 half2_t __attribute__((ext_vector_type(2)));

union PKH { unsigned u; half2_t h; };

__device__ __forceinline__ float sinrev_(float x) { return __builtin_amdgcn_sinf(x); }
__device__ __forceinline__ float cosrev_(float x) { return __builtin_amdgcn_cosf(x); }

__device__ __forceinline__ unsigned short bf16r(float x) {
    union { float f; unsigned u; } v; v.f = x;
    return (unsigned short)((v.u + 0x7FFFu + ((v.u >> 16) & 1u)) >> 16);
}

__device__ __forceinline__ short8 pack8(float4 a, float4 b, bool sq) {
    float v[8] = {a.x, a.y, a.z, a.w, b.x, b.y, b.z, b.w};
    short8 r;
#pragma unroll
    for (int i = 0; i < 8; ++i) { float x = sq ? v[i] * v[i] : v[i]; r[i] = (short)bf16r(x); }
    return r;
}

// ---------------------------------------------------------------------------
// K0: per-(b,d) precompute. 32 blocks x 256 thr.
// A1=cc^2, A2=-2mh'cc (bf16, [b][d]); XT = packed half2 (-cos,sin) [d][b];
// S0[b] = sum mh'^2.
// ---------------------------------------------------------------------------
__global__ __launch_bounds__(256)
void hake_prep(const int* __restrict__ e1, const int* __restrict__ rel,
               const float* __restrict__ emb_e, const float* __restrict__ emb_rel,
               char* __restrict__ ws)
{
    __shared__ float sp[4];
    const int b = blockIdx.x, d = threadIdx.x;
    const int he = e1[b], hr = rel[b];
    const float ph = emb_e[(size_t)he * 512 + d];
    const float mh = emb_e[(size_t)he * 512 + 256 + d];
    const float pr = emb_rel[(size_t)hr * 768 + d];
    const float mr = emb_rel[(size_t)hr * 768 + 256 + d];
    const float bi = emb_rel[(size_t)hr * 768 + 512 + d];

    const float a = (ph + pr) * K2S;
    PKH x;
    x.h.x = (_Float16)(-cosrev_(a));
    x.h.y = (_Float16)(sinrev_(a));
    ((unsigned*)(ws + WS_XT))[d * 32 + b] = x.u;   // [d][b] for coalesced main loads

    const float mra = fabsf(mr);
    float bic = fminf(bi, 1.0f);
    bic = (bic < -mra) ? -mra : bic;
    const float cc  = 1.0f - bic;
    const float mhp = mh * (mra + bic);
    ((short*)(ws + WS_A1))[b * 256 + d] = (short)bf16r(cc * cc);
    ((short*)(ws + WS_A2))[b * 256 + d] = (short)bf16r(-2.0f * mhp * cc);

    float s0 = mhp * mhp;
#pragma unroll
    for (int o = 1; o < 64; o <<= 1) s0 += __shfl_xor(s0, o, 64);
    if ((threadIdx.x & 63) == 0) sp[threadIdx.x >> 6] = s0;
    __syncthreads();
    if (threadIdx.x == 0)
        ((float*)(ws + WS_S0))[b] = sp[0] + sp[1] + sp[2] + sp[3];
}

// ---------------------------------------------------------------------------
// K1: r-term GEMM (R5-verified structure, A from ws). 313 blocks x 256 thr.
// Wave w -> 16-col tile. R[b,n] = S0_b + sum cc^2 mt^2 - 2 sum mh'cc mt.
// ---------------------------------------------------------------------------
__global__ __launch_bounds__(256)
void hake_rgemm(const float* __restrict__ emb_e, char* __restrict__ ws)
{
    const int t = threadIdx.x;
    const int w = t >> 6, l = t & 63;
    const int n0 = blockIdx.x * 64 + w * 16;
    if (n0 >= N_) return;                 // wave-uniform guard

    const short* A1w = (const short*)(ws + WS_A1);
    const short* A2w = (const short*)(ws + WS_A2);
    const float* S0w = (const float*)(ws + WS_S0);
    float*       Rw  = (float*)(ws + WS_R);

    const int fr   = l & 15;
    const int koff = (l >> 4) * 8;
    const float* mtp = emb_e + (size_t)(n0 + fr) * (2 * D_) + D_;

    f32x4 acc0 = {0.f, 0.f, 0.f, 0.f};
    f32x4 acc1 = {0.f, 0.f, 0.f, 0.f};
#pragma unroll
    for (int ch = 0; ch < 8; ++ch) {
        const int d = ch * 32 + koff;
        float4 va = *(const float4*)(mtp + d);
        float4 vb = *(const float4*)(mtp + d + 4);
        short8 b2f = pack8(va, vb, false);
        short8 b1f = pack8(va, vb, true);
        short8 a1_0 = *(const short8*)(A1w + fr * 256 + d);
        short8 a2_0 = *(const short8*)(A2w + fr * 256 + d);
        short8 a1_1 = *(const short8*)(A1w + (16 + fr) * 256 + d);
        short8 a2_1 = *(const short8*)(A2w + (16 + fr) * 256 + d);
        acc0 = __builtin_amdgcn_mfma_f32_16x16x32_bf16(a1_0, b1f, acc0, 0, 0, 0);
        acc0 = __builtin_amdgcn_mfma_f32_16x16x32_bf16(a2_0, b2f, acc0, 0, 0, 0);
        acc1 = __builtin_amdgcn_mfma_f32_16x16x32_bf16(a1_1, b1f, acc1, 0, 0, 0);
        acc1 = __builtin_amdgcn_mfma_f32_16x16x32_bf16(a2_1, b2f, acc1, 0, 0, 0);
    }

    // C/D map (verified): col = lane&15 (n), row = (lane>>4)*4 + reg (b)
#pragma unroll
    for (int r = 0; r < 4; ++r) {
        const int row = (l >> 4) * 4 + r;
        Rw[(size_t)row * N_ + n0 + fr]        = acc0[r] + S0w[row];
        Rw[(size_t)(16 + row) * N_ + n0 + fr] = acc1[r] + S0w[16 + row];
    }
}

// ---------------------------------------------------------------------------
// K2: phase + finalize. 1250 blocks x 512 thr. Spill-safe: short live ranges,
// individual Xr dword loads, scalar pad-17 redf writes, R loaded at finalize.
// LDS: Pb 16KB + redf 17.4KB = 33.8KB -> 4 blocks/CU. 2 barriers.
// ---------------------------------------------------------------------------
__global__ __launch_bounds__(512, 8)
void hake_main(const float* __restrict__ emb_e,
               const char* __restrict__ ws,
               const float* __restrict__ pw_p, const float* __restrict__ mw_p,
               float* __restrict__ out)
{
    __shared__ unsigned Pb[NT * 256];     // 16 KB packed (sb,cb) half2
    __shared__ float redf[8 * 32 * 17];   // 17.4 KB: [w][b][j] pad 17

    const int t   = threadIdx.x;
    const int l   = t & 63;
    const int w   = t >> 6;       // wave 0..7
    const int b   = t & 31;
    const int g   = t >> 5;       // d-group 0..15
    const int dlo = g * 16;
    const int n0  = blockIdx.x * NT;

    const unsigned* XTw = (const unsigned*)(ws + WS_XT);
    const float*    Rw  = (const float*)(ws + WS_R);

    // ---- phase-row loads and Pb staging (consume lp immediately) -----------
    {
        const float* prow0 = emb_e + (size_t)(n0 + w * 2) * (2 * D_);
        const float* prow1 = emb_e + (size_t)(n0 + w * 2 + 1) * (2 * D_);
        float2 lp00 = *(const float2*)(prow0 + 2 * l);
        float2 lp01 = *(const float2*)(prow0 + 128 + 2 * l);
        float2 lp10 = *(const float2*)(prow1 + 2 * l);
        float2 lp11 = *(const float2*)(prow1 + 128 + 2 * l);

        PKH w0, w1;
        float v0, v1;
        v0 = lp00.x * K2S; v1 = lp00.y * K2S;
        w0.h.x = (_Float16)sinrev_(v0); w0.h.y = (_Float16)cosrev_(v0);
        w1.h.x = (_Float16)sinrev_(v1); w1.h.y = (_Float16)cosrev_(v1);
        *(uint2*)(&Pb[(w * 2) * 256 + 2 * l]) = make_uint2(w0.u, w1.u);
        v0 = lp01.x * K2S; v1 = lp01.y * K2S;
        w0.h.x = (_Float16)sinrev_(v0); w0.h.y = (_Float16)cosrev_(v0);
        w1.h.x = (_Float16)sinrev_(v1); w1.h.y = (_Float16)cosrev_(v1);
        *(uint2*)(&Pb[(w * 2) * 256 + 128 + 2 * l]) = make_uint2(w0.u, w1.u);
        v0 = lp10.x * K2S; v1 = lp10.y * K2S;
        w0.h.x = (_Float16)sinrev_(v0); w0.h.y = (_Float16)cosrev_(v0);
        w1.h.x = (_Float16)sinrev_(v1); w1.h.y = (_Float16)cosrev_(v1);
        *(uint2*)(&Pb[(w * 2 + 1) * 256 + 2 * l]) = make_uint2(w0.u, w1.u);
        v0 = lp11.x * K2S; v1 = lp11.y * K2S;
        w0.h.x = (_Float16)sinrev_(v0); w0.h.y = (_Float16)cosrev_(v0);
        w1.h.x = (_Float16)sinrev_(v1); w1.h.y = (_Float16)cosrev_(v1);
        *(uint2*)(&Pb[(w * 2 + 1) * 256 + 128 + 2 * l]) = make_uint2(w0.u, w1.u);
    }

    // ---- Xr: 16 individual coalesced dword loads (L2-hot, 32KB table) ------
    half2_t Xr[16];
#pragma unroll
    for (int i = 0; i < 16; ++i)
        Xr[i] = __builtin_bit_cast(half2_t, XTw[(dlo + i) * 32 + b]);

    __syncthreads();                                    // b1: Pb ready

    // ---- phase accumulate: dot2 + abs-add ----------------------------------
    float sph[NT];
#pragma unroll
    for (int j = 0; j < NT; ++j) sph[j] = 0.0f;

#pragma unroll
    for (int q = 0; q < 4; ++q) {
        const half2_t x0 = Xr[q * 4 + 0];
        const half2_t x1 = Xr[q * 4 + 1];
        const half2_t x2 = Xr[q * 4 + 2];
        const half2_t x3 = Xr[q * 4 + 3];
#pragma unroll
        for (int j = 0; j < NT; ++j) {
            uint4 tv = *(const uint4*)(&Pb[j * 256 + dlo + q * 4]);   // bcast
            sph[j] += fabsf(__builtin_amdgcn_fdot2(x0, __builtin_bit_cast(half2_t, tv.x), 0.0f, false));
            sph[j] += fabsf(__builtin_amdgcn_fdot2(x1, __builtin_bit_cast(half2_t, tv.y), 0.0f, false));
            sph[j] += fabsf(__builtin_amdgcn_fdot2(x2, __builtin_bit_cast(half2_t, tv.z), 0.0f, false));
            sph[j] += fabsf(__builtin_amdgcn_fdot2(x3, __builtin_bit_cast(half2_t, tv.w), 0.0f, false));
        }
    }

    // ---- reduce: half-wave combine, then scalar writes [w][b=l][j] ---------
#pragma unroll
    for (int j = 0; j < NT; ++j) sph[j] += __shfl_xor(sph[j], 32, 64);
    if (l < 32) {
#pragma unroll
        for (int j = 0; j < NT; ++j) redf[(w * 32 + l) * 17 + j] = sph[j];
    }
    __syncthreads();                                    // b2: redf ready

    // ---- finalize: thread -> (b = t>>4, n = n0 + (t&15)), coalesced --------
    {
        const int fn = t & 15, fb = t >> 4;
        float pa = 0.0f;
#pragma unroll
        for (int ww = 0; ww < 8; ++ww) pa += redf[(ww * 32 + fb) * 17 + fn];
        float rfull = fmaxf(Rw[(size_t)fb * N_ + n0 + fn], 0.0f);
        float z = fmaf(pa, pw_p[0], sqrtf(rfull) * mw_p[0]) - 12.0f;  // GAMMA
        out[(size_t)fb * N_ + (n0 + fn)] = 1.0f / (1.0f + __expf(z));
    }
}

extern "C" void kernel_launch(void* const* d_in, const int* in_sizes, int n_in,
                              void* d_out, int out_size, void* d_ws, size_t ws_size,
                              hipStream_t stream)
{
    // inputs: 0:g 1:e1 2:rel 3:e2_multi(unused) 4:emb_e 5:emb_rel 6:phase_w 7:mod_w
    const int*   e1      = (const int*)d_in[1];
    const int*   rel     = (const int*)d_in[2];
    const float* emb_e   = (const float*)d_in[4];
    const float* emb_rel = (const float*)d_in[5];
    const float* pw      = (const float*)d_in[6];
    const float* mw      = (const float*)d_in[7];
    float* out = (float*)d_out;

    hipLaunchKernelGGL(hake_prep, dim3(32), dim3(256), 0, stream,
                       e1, rel, emb_e, emb_rel, (char*)d_ws);
    hipLaunchKernelGGL(hake_rgemm, dim3(313), dim3(256), 0, stream,
                       emb_e, (char*)d_ws);
    hipLaunchKernelGGL(hake_main, dim3(NBLK), dim3(512), 0, stream,
                       emb_e, (const char*)d_ws, pw, mw, out);
}

// Round 14
// 97.027 us; speedup vs baseline: 1.2049x; 1.1851x over previous
//
#include <hip/hip_runtime.h>
#include <math.h>

// HAKE scoring for MI355X — round 14: R13 pipeline, spill fixed via lb(512,6).
// R12/R13 lesson: pure-phase main at lb(512,8) (cap 64 VGPR) spills
// catastrophically (VGPR_Count 32, WRITE 258MB) regardless of live-range
// ordering; R7 proved lb(512,6) (cap 85) allocates cleanly. One variable
// changed vs R13: the launch bound (+ R read hoisted above the inner loop).
// This is the clean test of the gather-elimination theory.

#define D_   256
#define N_   20000
#define NT   16
#define NBLK (N_ / NT)      // 1250

// rev units for sin(x/2): 1/(4*EMB_RANGE)
#define K2S 4.571428571428571f

// ws layout (bytes)
#define WS_A1 0          // 32x256 bf16
#define WS_A2 16384      // 32x256 bf16
#define WS_XT 32768      // 256x32 u32 (packed half2 (-cos,sin)), [d][b]
#define WS_S0 65536      // 32 f32
#define WS_R  65792      // 32x20000 f32

typedef short short8 __attribute__((ext_vector_type(8)));
typedef float f32x4  __attribute__((ext_vector_type(4)));
typedef _Float16 half2_t __attribute__((ext_vector_type(2)));

union PKH { unsigned u; half2_t h; };

__device__ __forceinline__ float sinrev_(float x) { return __builtin_amdgcn_sinf(x); }
__device__ __forceinline__ float cosrev_(float x) { return __builtin_amdgcn_cosf(x); }

__device__ __forceinline__ unsigned short bf16r(float x) {
    union { float f; unsigned u; } v; v.f = x;
    return (unsigned short)((v.u + 0x7FFFu + ((v.u >> 16) & 1u)) >> 16);
}

__device__ __forceinline__ short8 pack8(float4 a, float4 b, bool sq) {
    float v[8] = {a.x, a.y, a.z, a.w, b.x, b.y, b.z, b.w};
    short8 r;
#pragma unroll
    for (int i = 0; i < 8; ++i) { float x = sq ? v[i] * v[i] : v[i]; r[i] = (short)bf16r(x); }
    return r;
}

// ---------------------------------------------------------------------------
// K0: per-(b,d) precompute. 32 blocks x 256 thr.
// A1=cc^2, A2=-2mh'cc (bf16, [b][d]); XT = packed half2 (-cos,sin) [d][b];
// S0[b] = sum mh'^2.
// ---------------------------------------------------------------------------
__global__ __launch_bounds__(256)
void hake_prep(const int* __restrict__ e1, const int* __restrict__ rel,
               const float* __restrict__ emb_e, const float* __restrict__ emb_rel,
               char* __restrict__ ws)
{
    __shared__ float sp[4];
    const int b = blockIdx.x, d = threadIdx.x;
    const int he = e1[b], hr = rel[b];
    const float ph = emb_e[(size_t)he * 512 + d];
    const float mh = emb_e[(size_t)he * 512 + 256 + d];
    const float pr = emb_rel[(size_t)hr * 768 + d];
    const float mr = emb_rel[(size_t)hr * 768 + 256 + d];
    const float bi = emb_rel[(size_t)hr * 768 + 512 + d];

    const float a = (ph + pr) * K2S;
    PKH x;
    x.h.x = (_Float16)(-cosrev_(a));
    x.h.y = (_Float16)(sinrev_(a));
    ((unsigned*)(ws + WS_XT))[d * 32 + b] = x.u;   // [d][b] for coalesced main loads

    const float mra = fabsf(mr);
    float bic = fminf(bi, 1.0f);
    bic = (bic < -mra) ? -mra : bic;
    const float cc  = 1.0f - bic;
    const float mhp = mh * (mra + bic);
    ((short*)(ws + WS_A1))[b * 256 + d] = (short)bf16r(cc * cc);
    ((short*)(ws + WS_A2))[b * 256 + d] = (short)bf16r(-2.0f * mhp * cc);

    float s0 = mhp * mhp;
#pragma unroll
    for (int o = 1; o < 64; o <<= 1) s0 += __shfl_xor(s0, o, 64);
    if ((threadIdx.x & 63) == 0) sp[threadIdx.x >> 6] = s0;
    __syncthreads();
    if (threadIdx.x == 0)
        ((float*)(ws + WS_S0))[b] = sp[0] + sp[1] + sp[2] + sp[3];
}

// ---------------------------------------------------------------------------
// K1: r-term GEMM (R5-verified structure, A from ws). 313 blocks x 256 thr.
// Wave w -> 16-col tile. R[b,n] = S0_b + sum cc^2 mt^2 - 2 sum mh'cc mt.
// ---------------------------------------------------------------------------
__global__ __launch_bounds__(256)
void hake_rgemm(const float* __restrict__ emb_e, char* __restrict__ ws)
{
    const int t = threadIdx.x;
    const int w = t >> 6, l = t & 63;
    const int n0 = blockIdx.x * 64 + w * 16;
    if (n0 >= N_) return;                 // wave-uniform guard

    const short* A1w = (const short*)(ws + WS_A1);
    const short* A2w = (const short*)(ws + WS_A2);
    const float* S0w = (const float*)(ws + WS_S0);
    float*       Rw  = (float*)(ws + WS_R);

    const int fr   = l & 15;
    const int koff = (l >> 4) * 8;
    const float* mtp = emb_e + (size_t)(n0 + fr) * (2 * D_) + D_;

    f32x4 acc0 = {0.f, 0.f, 0.f, 0.f};
    f32x4 acc1 = {0.f, 0.f, 0.f, 0.f};
#pragma unroll
    for (int ch = 0; ch < 8; ++ch) {
        const int d = ch * 32 + koff;
        float4 va = *(const float4*)(mtp + d);
        float4 vb = *(const float4*)(mtp + d + 4);
        short8 b2f = pack8(va, vb, false);
        short8 b1f = pack8(va, vb, true);
        short8 a1_0 = *(const short8*)(A1w + fr * 256 + d);
        short8 a2_0 = *(const short8*)(A2w + fr * 256 + d);
        short8 a1_1 = *(const short8*)(A1w + (16 + fr) * 256 + d);
        short8 a2_1 = *(const short8*)(A2w + (16 + fr) * 256 + d);
        acc0 = __builtin_amdgcn_mfma_f32_16x16x32_bf16(a1_0, b1f, acc0, 0, 0, 0);
        acc0 = __builtin_amdgcn_mfma_f32_16x16x32_bf16(a2_0, b2f, acc0, 0, 0, 0);
        acc1 = __builtin_amdgcn_mfma_f32_16x16x32_bf16(a1_1, b1f, acc1, 0, 0, 0);
        acc1 = __builtin_amdgcn_mfma_f32_16x16x32_bf16(a2_1, b2f, acc1, 0, 0, 0);
    }

    // C/D map (verified): col = lane&15 (n), row = (lane>>4)*4 + reg (b)
#pragma unroll
    for (int r = 0; r < 4; ++r) {
        const int row = (l >> 4) * 4 + r;
        Rw[(size_t)row * N_ + n0 + fr]        = acc0[r] + S0w[row];
        Rw[(size_t)(16 + row) * N_ + n0 + fr] = acc1[r] + S0w[16 + row];
    }
}

// ---------------------------------------------------------------------------
// K2: phase + finalize. 1250 blocks x 512 thr, lb(512,6) -> cap 85 VGPR,
// 3 blocks/CU, 24 waves/CU. All global traffic coalesced. 2 barriers.
// ---------------------------------------------------------------------------
__global__ __launch_bounds__(512, 6)
void hake_main(const float* __restrict__ emb_e,
               const char* __restrict__ ws,
               const float* __restrict__ pw_p, const float* __restrict__ mw_p,
               float* __restrict__ out)
{
    __shared__ unsigned Pb[NT * 256];     // 16 KB packed (sb,cb) half2
    __shared__ float redf[8 * 32 * 17];   // 17.4 KB: [w][b][j] pad 17

    const int t   = threadIdx.x;
    const int l   = t & 63;
    const int w   = t >> 6;       // wave 0..7
    const int b   = t & 31;
    const int g   = t >> 5;       // d-group 0..15
    const int dlo = g * 16;
    const int n0  = blockIdx.x * NT;

    const unsigned* XTw = (const unsigned*)(ws + WS_XT);
    const float*    Rw  = (const float*)(ws + WS_R);

    // ---- phase-row loads and Pb staging (consume lp immediately) -----------
    {
        const float* prow0 = emb_e + (size_t)(n0 + w * 2) * (2 * D_);
        const float* prow1 = emb_e + (size_t)(n0 + w * 2 + 1) * (2 * D_);
        float2 lp00 = *(const float2*)(prow0 + 2 * l);
        float2 lp01 = *(const float2*)(prow0 + 128 + 2 * l);
        float2 lp10 = *(const float2*)(prow1 + 2 * l);
        float2 lp11 = *(const float2*)(prow1 + 128 + 2 * l);

        PKH w0, w1;
        float v0, v1;
        v0 = lp00.x * K2S; v1 = lp00.y * K2S;
        w0.h.x = (_Float16)sinrev_(v0); w0.h.y = (_Float16)cosrev_(v0);
        w1.h.x = (_Float16)sinrev_(v1); w1.h.y = (_Float16)cosrev_(v1);
        *(uint2*)(&Pb[(w * 2) * 256 + 2 * l]) = make_uint2(w0.u, w1.u);
        v0 = lp01.x * K2S; v1 = lp01.y * K2S;
        w0.h.x = (_Float16)sinrev_(v0); w0.h.y = (_Float16)cosrev_(v0);
        w1.h.x = (_Float16)sinrev_(v1); w1.h.y = (_Float16)cosrev_(v1);
        *(uint2*)(&Pb[(w * 2) * 256 + 128 + 2 * l]) = make_uint2(w0.u, w1.u);
        v0 = lp10.x * K2S; v1 = lp10.y * K2S;
        w0.h.x = (_Float16)sinrev_(v0); w0.h.y = (_Float16)cosrev_(v0);
        w1.h.x = (_Float16)sinrev_(v1); w1.h.y = (_Float16)cosrev_(v1);
        *(uint2*)(&Pb[(w * 2 + 1) * 256 + 2 * l]) = make_uint2(w0.u, w1.u);
        v0 = lp11.x * K2S; v1 = lp11.y * K2S;
        w0.h.x = (_Float16)sinrev_(v0); w0.h.y = (_Float16)cosrev_(v0);
        w1.h.x = (_Float16)sinrev_(v1); w1.h.y = (_Float16)cosrev_(v1);
        *(uint2*)(&Pb[(w * 2 + 1) * 256 + 128 + 2 * l]) = make_uint2(w0.u, w1.u);
    }

    // ---- Xr: 16 coalesced dword loads (L2-hot, 32KB table) -----------------
    half2_t Xr[16];
#pragma unroll
    for (int i = 0; i < 16; ++i)
        Xr[i] = __builtin_bit_cast(half2_t, XTw[(dlo + i) * 32 + b]);

    __syncthreads();                                    // b1: Pb ready

    // ---- R read issued early: latency hides under the inner loop -----------
    const int fn = t & 15, fb = t >> 4;
    const float rpre = Rw[(size_t)fb * N_ + n0 + fn];

    // ---- phase accumulate: dot2 + abs-add ----------------------------------
    float sph[NT];
#pragma unroll
    for (int j = 0; j < NT; ++j) sph[j] = 0.0f;

#pragma unroll
    for (int q = 0; q < 4; ++q) {
        const half2_t x0 = Xr[q * 4 + 0];
        const half2_t x1 = Xr[q * 4 + 1];
        const half2_t x2 = Xr[q * 4 + 2];
        const half2_t x3 = Xr[q * 4 + 3];
#pragma unroll
        for (int j = 0; j < NT; ++j) {
            uint4 tv = *(const uint4*)(&Pb[j * 256 + dlo + q * 4]);   // bcast
            sph[j] += fabsf(__builtin_amdgcn_fdot2(x0, __builtin_bit_cast(half2_t, tv.x), 0.0f, false));
            sph[j] += fabsf(__builtin_amdgcn_fdot2(x1, __builtin_bit_cast(half2_t, tv.y), 0.0f, false));
            sph[j] += fabsf(__builtin_amdgcn_fdot2(x2, __builtin_bit_cast(half2_t, tv.z), 0.0f, false));
            sph[j] += fabsf(__builtin_amdgcn_fdot2(x3, __builtin_bit_cast(half2_t, tv.w), 0.0f, false));
        }
    }

    // ---- reduce: half-wave combine, then scalar writes [w][b=l][j] ---------
#pragma unroll
    for (int j = 0; j < NT; ++j) sph[j] += __shfl_xor(sph[j], 32, 64);
    if (l < 32) {
#pragma unroll
        for (int j = 0; j < NT; ++j) redf[(w * 32 + l) * 17 + j] = sph[j];
    }
    __syncthreads();                                    // b2: redf ready

    // ---- finalize: thread -> (b = t>>4, n = n0 + (t&15)), coalesced --------
    {
        float pa = 0.0f;
#pragma unroll
        for (int ww = 0; ww < 8; ++ww) pa += redf[(ww * 32 + fb) * 17 + fn];
        float rfull = fmaxf(rpre, 0.0f);
        float z = fmaf(pa, pw_p[0], sqrtf(rfull) * mw_p[0]) - 12.0f;  // GAMMA
        out[(size_t)fb * N_ + (n0 + fn)] = 1.0f / (1.0f + __expf(z));
    }
}

extern "C" void kernel_launch(void* const* d_in, const int* in_sizes, int n_in,
                              void* d_out, int out_size, void* d_ws, size_t ws_size,
                              hipStream_t stream)
{
    // inputs: 0:g 1:e1 2:rel 3:e2_multi(unused) 4:emb_e 5:emb_rel 6:phase_w 7:mod_w
    const int*   e1      = (const int*)d_in[1];
    const int*   rel     = (const int*)d_in[2];
    const float* emb_e   = (const float*)d_in[4];
    const float* emb_rel = (const float*)d_in[5];
    const float* pw      = (const float*)d_in[6];
    const float* mw      = (const float*)d_in[7];
    float* out = (float*)d_out;

    hipLaunchKernelGGL(hake_prep, dim3(32), dim3(256), 0, stream,
                       e1, rel, emb_e, emb_rel, (char*)d_ws);
    hipLaunchKernelGGL(hake_rgemm, dim3(313), dim3(256), 0, stream,
                       emb_e, (char*)d_ws);
    hipLaunchKernelGGL(hake_main, dim3(NBLK), dim3(512), 0, stream,
                       emb_e, (const char*)d_ws, pw, mw, out);
}

// Round 15
// 54.794 us; speedup vs baseline: 2.1336x; 1.7708x over previous
//
#include <hip/hip_runtime.h>
#include <math.h>

// HAKE scoring for MI355X — round 15: pipeline with a 256-thread main.
// R12-R14 lesson: the 512-thread pure-phase main spills pathologically under
// every live-range ordering tried (WRITE 189-274MB, VGPR 32-40). Change the
// SHAPE: 256 thr, NT=8, thread owns 32 d (Xr[32]+sph[8] ~ 60 live regs),
// lb(256,5) cap 102 -> ~40 regs headroom. prep/rgemm unchanged (clean).
// This finally tests the gather-elimination theory on clean codegen.

#define D_   256
#define N_   20000
#define NT   8
#define NBLK (N_ / NT)      // 2500

// rev units for sin(x/2): 1/(4*EMB_RANGE)
#define K2S 4.571428571428571f

// ws layout (bytes)
#define WS_A1 0          // 32x256 bf16
#define WS_A2 16384      // 32x256 bf16
#define WS_XT 32768      // 256x32 u32 (packed half2 (-cos,sin)), [d][b]
#define WS_S0 65536      // 32 f32
#define WS_R  65792      // 32x20000 f32

typedef short short8 __attribute__((ext_vector_type(8)));
typedef float f32x4  __attribute__((ext_vector_type(4)));
typedef _Float16 half2_t __attribute__((ext_vector_type(2)));

union PKH { unsigned u; half2_t h; };

__device__ __forceinline__ float sinrev_(float x) { return __builtin_amdgcn_sinf(x); }
__device__ __forceinline__ float cosrev_(float x) { return __builtin_amdgcn_cosf(x); }

__device__ __forceinline__ unsigned short bf16r(float x) {
    union { float f; unsigned u; } v; v.f = x;
    return (unsigned short)((v.u + 0x7FFFu + ((v.u >> 16) & 1u)) >> 16);
}

__device__ __forceinline__ short8 pack8(float4 a, float4 b, bool sq) {
    float v[8] = {a.x, a.y, a.z, a.w, b.x, b.y, b.z, b.w};
    short8 r;
#pragma unroll
    for (int i = 0; i < 8; ++i) { float x = sq ? v[i] * v[i] : v[i]; r[i] = (short)bf16r(x); }
    return r;
}

// ---------------------------------------------------------------------------
// K0: per-(b,d) precompute. 32 blocks x 256 thr. (unchanged, proven clean)
// ---------------------------------------------------------------------------
__global__ __launch_bounds__(256)
void hake_prep(const int* __restrict__ e1, const int* __restrict__ rel,
               const float* __restrict__ emb_e, const float* __restrict__ emb_rel,
               char* __restrict__ ws)
{
    __shared__ float sp[4];
    const int b = blockIdx.x, d = threadIdx.x;
    const int he = e1[b], hr = rel[b];
    const float ph = emb_e[(size_t)he * 512 + d];
    const float mh = emb_e[(size_t)he * 512 + 256 + d];
    const float pr = emb_rel[(size_t)hr * 768 + d];
    const float mr = emb_rel[(size_t)hr * 768 + 256 + d];
    const float bi = emb_rel[(size_t)hr * 768 + 512 + d];

    const float a = (ph + pr) * K2S;
    PKH x;
    x.h.x = (_Float16)(-cosrev_(a));
    x.h.y = (_Float16)(sinrev_(a));
    ((unsigned*)(ws + WS_XT))[d * 32 + b] = x.u;   // [d][b] for coalesced main loads

    const float mra = fabsf(mr);
    float bic = fminf(bi, 1.0f);
    bic = (bic < -mra) ? -mra : bic;
    const float cc  = 1.0f - bic;
    const float mhp = mh * (mra + bic);
    ((short*)(ws + WS_A1))[b * 256 + d] = (short)bf16r(cc * cc);
    ((short*)(ws + WS_A2))[b * 256 + d] = (short)bf16r(-2.0f * mhp * cc);

    float s0 = mhp * mhp;
#pragma unroll
    for (int o = 1; o < 64; o <<= 1) s0 += __shfl_xor(s0, o, 64);
    if ((threadIdx.x & 63) == 0) sp[threadIdx.x >> 6] = s0;
    __syncthreads();
    if (threadIdx.x == 0)
        ((float*)(ws + WS_S0))[b] = sp[0] + sp[1] + sp[2] + sp[3];
}

// ---------------------------------------------------------------------------
// K1: r-term GEMM (unchanged, proven clean). 313 blocks x 256 thr.
// ---------------------------------------------------------------------------
__global__ __launch_bounds__(256)
void hake_rgemm(const float* __restrict__ emb_e, char* __restrict__ ws)
{
    const int t = threadIdx.x;
    const int w = t >> 6, l = t & 63;
    const int n0 = blockIdx.x * 64 + w * 16;
    if (n0 >= N_) return;                 // wave-uniform guard

    const short* A1w = (const short*)(ws + WS_A1);
    const short* A2w = (const short*)(ws + WS_A2);
    const float* S0w = (const float*)(ws + WS_S0);
    float*       Rw  = (float*)(ws + WS_R);

    const int fr   = l & 15;
    const int koff = (l >> 4) * 8;
    const float* mtp = emb_e + (size_t)(n0 + fr) * (2 * D_) + D_;

    f32x4 acc0 = {0.f, 0.f, 0.f, 0.f};
    f32x4 acc1 = {0.f, 0.f, 0.f, 0.f};
#pragma unroll
    for (int ch = 0; ch < 8; ++ch) {
        const int d = ch * 32 + koff;
        float4 va = *(const float4*)(mtp + d);
        float4 vb = *(const float4*)(mtp + d + 4);
        short8 b2f = pack8(va, vb, false);
        short8 b1f = pack8(va, vb, true);
        short8 a1_0 = *(const short8*)(A1w + fr * 256 + d);
        short8 a2_0 = *(const short8*)(A2w + fr * 256 + d);
        short8 a1_1 = *(const short8*)(A1w + (16 + fr) * 256 + d);
        short8 a2_1 = *(const short8*)(A2w + (16 + fr) * 256 + d);
        acc0 = __builtin_amdgcn_mfma_f32_16x16x32_bf16(a1_0, b1f, acc0, 0, 0, 0);
        acc0 = __builtin_amdgcn_mfma_f32_16x16x32_bf16(a2_0, b2f, acc0, 0, 0, 0);
        acc1 = __builtin_amdgcn_mfma_f32_16x16x32_bf16(a1_1, b1f, acc1, 0, 0, 0);
        acc1 = __builtin_amdgcn_mfma_f32_16x16x32_bf16(a2_1, b2f, acc1, 0, 0, 0);
    }

    // C/D map (verified): col = lane&15 (n), row = (lane>>4)*4 + reg (b)
#pragma unroll
    for (int r = 0; r < 4; ++r) {
        const int row = (l >> 4) * 4 + r;
        Rw[(size_t)row * N_ + n0 + fr]        = acc0[r] + S0w[row];
        Rw[(size_t)(16 + row) * N_ + n0 + fr] = acc1[r] + S0w[16 + row];
    }
}

// ---------------------------------------------------------------------------
// K2: phase + finalize. 2500 blocks x 256 thr, lb(256,5) -> cap 102 VGPR,
// 5 blocks/CU = 20 waves/CU. Thread owns (b, 32 d); wave w stages rows
// 2w,2w+1. LDS 12.6KB. 2 barriers. All traffic coalesced.
// ---------------------------------------------------------------------------
__global__ __launch_bounds__(256, 5)
void hake_main(const float* __restrict__ emb_e,
               const char* __restrict__ ws,
               const float* __restrict__ pw_p, const float* __restrict__ mw_p,
               float* __restrict__ out)
{
    __shared__ unsigned Pb[NT * 256];    // 8 KB packed (sb,cb) half2
    __shared__ float redf[4 * 32 * 9];   // 4.6 KB: [w][b][j] pad 9

    const int t   = threadIdx.x;
    const int l   = t & 63;
    const int w   = t >> 6;       // wave 0..3
    const int b   = t & 31;
    const int g   = t >> 5;       // d-group 0..7 (32 d each)
    const int dlo = g * 32;
    const int n0  = blockIdx.x * NT;

    const unsigned* XTw = (const unsigned*)(ws + WS_XT);
    const float*    Rw  = (const float*)(ws + WS_R);

    // ---- stage Pb: wave w -> rows 2w, 2w+1 (consume lp immediately) --------
    {
        const float* prow0 = emb_e + (size_t)(n0 + w * 2) * (2 * D_);
        const float* prow1 = emb_e + (size_t)(n0 + w * 2 + 1) * (2 * D_);
        float2 lp00 = *(const float2*)(prow0 + 2 * l);
        float2 lp01 = *(const float2*)(prow0 + 128 + 2 * l);
        float2 lp10 = *(const float2*)(prow1 + 2 * l);
        float2 lp11 = *(const float2*)(prow1 + 128 + 2 * l);

        PKH w0, w1;
        float v0, v1;
        v0 = lp00.x * K2S; v1 = lp00.y * K2S;
        w0.h.x = (_Float16)sinrev_(v0); w0.h.y = (_Float16)cosrev_(v0);
        w1.h.x = (_Float16)sinrev_(v1); w1.h.y = (_Float16)cosrev_(v1);
        *(uint2*)(&Pb[(w * 2) * 256 + 2 * l]) = make_uint2(w0.u, w1.u);
        v0 = lp01.x * K2S; v1 = lp01.y * K2S;
        w0.h.x = (_Float16)sinrev_(v0); w0.h.y = (_Float16)cosrev_(v0);
        w1.h.x = (_Float16)sinrev_(v1); w1.h.y = (_Float16)cosrev_(v1);
        *(uint2*)(&Pb[(w * 2) * 256 + 128 + 2 * l]) = make_uint2(w0.u, w1.u);
        v0 = lp10.x * K2S; v1 = lp10.y * K2S;
        w0.h.x = (_Float16)sinrev_(v0); w0.h.y = (_Float16)cosrev_(v0);
        w1.h.x = (_Float16)sinrev_(v1); w1.h.y = (_Float16)cosrev_(v1);
        *(uint2*)(&Pb[(w * 2 + 1) * 256 + 2 * l]) = make_uint2(w0.u, w1.u);
        v0 = lp11.x * K2S; v1 = lp11.y * K2S;
        w0.h.x = (_Float16)sinrev_(v0); w0.h.y = (_Float16)cosrev_(v0);
        w1.h.x = (_Float16)sinrev_(v1); w1.h.y = (_Float16)cosrev_(v1);
        *(uint2*)(&Pb[(w * 2 + 1) * 256 + 128 + 2 * l]) = make_uint2(w0.u, w1.u);
    }

    // ---- Xr: 32 coalesced dword loads, one base + imm offsets (L2-hot) -----
    half2_t Xr[32];
    {
        const unsigned* xb = XTw + dlo * 32 + b;
#pragma unroll
        for (int i = 0; i < 32; ++i)
            Xr[i] = __builtin_bit_cast(half2_t, xb[i * 32]);
    }

    __syncthreads();                                    // b1: Pb ready

    // ---- R prefetch (latency hides under inner loop) -----------------------
    const int fn = t & 7, fb = t >> 3;
    const float rpre = Rw[(size_t)fb * N_ + n0 + fn];

    // ---- phase accumulate: 32 d x 8 n; dot2 + abs-add ----------------------
    float sph[NT];
#pragma unroll
    for (int j = 0; j < NT; ++j) sph[j] = 0.0f;

#pragma unroll
    for (int q = 0; q < 8; ++q) {
        const half2_t x0 = Xr[q * 4 + 0];
        const half2_t x1 = Xr[q * 4 + 1];
        const half2_t x2 = Xr[q * 4 + 2];
        const half2_t x3 = Xr[q * 4 + 3];
#pragma unroll
        for (int j = 0; j < NT; ++j) {
            uint4 tv = *(const uint4*)(&Pb[j * 256 + dlo + q * 4]);   // bcast
            sph[j] += fabsf(__builtin_amdgcn_fdot2(x0, __builtin_bit_cast(half2_t, tv.x), 0.0f, false));
            sph[j] += fabsf(__builtin_amdgcn_fdot2(x1, __builtin_bit_cast(half2_t, tv.y), 0.0f, false));
            sph[j] += fabsf(__builtin_amdgcn_fdot2(x2, __builtin_bit_cast(half2_t, tv.z), 0.0f, false));
            sph[j] += fabsf(__builtin_amdgcn_fdot2(x3, __builtin_bit_cast(half2_t, tv.w), 0.0f, false));
        }
    }

    // ---- reduce: half-wave combine, scalar writes [w][b=l][j] --------------
#pragma unroll
    for (int j = 0; j < NT; ++j) sph[j] += __shfl_xor(sph[j], 32, 64);
    if (l < 32) {
#pragma unroll
        for (int j = 0; j < NT; ++j) redf[(w * 32 + l) * 9 + j] = sph[j];
    }
    __syncthreads();                                    // b2: redf ready

    // ---- finalize: thread -> (b = t>>3, n = n0 + (t&7)) --------------------
    {
        float pa = 0.0f;
#pragma unroll
        for (int ww = 0; ww < 4; ++ww) pa += redf[(ww * 32 + fb) * 9 + fn];
        float rfull = fmaxf(rpre, 0.0f);
        float z = fmaf(pa, pw_p[0], sqrtf(rfull) * mw_p[0]) - 12.0f;  // GAMMA
        out[(size_t)fb * N_ + (n0 + fn)] = 1.0f / (1.0f + __expf(z));
    }
}

extern "C" void kernel_launch(void* const* d_in, const int* in_sizes, int n_in,
                              void* d_out, int out_size, void* d_ws, size_t ws_size,
                              hipStream_t stream)
{
    // inputs: 0:g 1:e1 2:rel 3:e2_multi(unused) 4:emb_e 5:emb_rel 6:phase_w 7:mod_w
    const int*   e1      = (const int*)d_in[1];
    const int*   rel     = (const int*)d_in[2];
    const float* emb_e   = (const float*)d_in[4];
    const float* emb_rel = (const float*)d_in[5];
    const float* pw      = (const float*)d_in[6];
    const float* mw      = (const float*)d_in[7];
    float* out = (float*)d_out;

    hipLaunchKernelGGL(hake_prep, dim3(32), dim3(256), 0, stream,
                       e1, rel, emb_e, emb_rel, (char*)d_ws);
    hipLaunchKernelGGL(hake_rgemm, dim3(313), dim3(256), 0, stream,
                       emb_e, (char*)d_ws);
    hipLaunchKernelGGL(hake_main, dim3(NBLK), dim3(256), 0, stream,
                       emb_e, (const char*)d_ws, pw, mw, out);
}

// Round 16
// 44.911 us; speedup vs baseline: 2.6032x; 1.2201x over previous
//
#include <hip/hip_runtime.h>
#include <math.h>

// HAKE scoring for MI355X — round 16: kill the spill trigger itself.
// R12-R15 lesson: 4 shapes, 4 spills; common trigger = big per-thread reg
// array (Xr[16..32]) live across a flat fully-unrolled inner loop -> unroller
// hoists LDS reads, pressure explodes, allocator dumps array to scratch.
// Fix: X loaded 4-at-a-time INSIDE a '#pragma unroll 1' q-loop from the 32KB
// L1-resident XT table; no min-waves cap. Live regs ~25-45. prep/rgemm
// unchanged (proven).

#define D_   256
#define N_   20000
#define NT   8
#define NBLK (N_ / NT)      // 2500

// rev units for sin(x/2): 1/(4*EMB_RANGE)
#define K2S 4.571428571428571f

// ws layout (bytes)
#define WS_A1 0          // 32x256 bf16
#define WS_A2 16384      // 32x256 bf16
#define WS_XT 32768      // 256x32 u32 (packed half2 (-cos,sin)), [d][b]
#define WS_S0 65536      // 32 f32
#define WS_R  65792      // 32x20000 f32

typedef short short8 __attribute__((ext_vector_type(8)));
typedef float f32x4  __attribute__((ext_vector_type(4)));
typedef _Float16 half2_t __attribute__((ext_vector_type(2)));

union PKH { unsigned u; half2_t h; };

__device__ __forceinline__ float sinrev_(float x) { return __builtin_amdgcn_sinf(x); }
__device__ __forceinline__ float cosrev_(float x) { return __builtin_amdgcn_cosf(x); }

__device__ __forceinline__ unsigned short bf16r(float x) {
    union { float f; unsigned u; } v; v.f = x;
    return (unsigned short)((v.u + 0x7FFFu + ((v.u >> 16) & 1u)) >> 16);
}

__device__ __forceinline__ short8 pack8(float4 a, float4 b, bool sq) {
    float v[8] = {a.x, a.y, a.z, a.w, b.x, b.y, b.z, b.w};
    short8 r;
#pragma unroll
    for (int i = 0; i < 8; ++i) { float x = sq ? v[i] * v[i] : v[i]; r[i] = (short)bf16r(x); }
    return r;
}

// ---------------------------------------------------------------------------
// K0: per-(b,d) precompute. 32 blocks x 256 thr. (unchanged, proven clean)
// ---------------------------------------------------------------------------
__global__ __launch_bounds__(256)
void hake_prep(const int* __restrict__ e1, const int* __restrict__ rel,
               const float* __restrict__ emb_e, const float* __restrict__ emb_rel,
               char* __restrict__ ws)
{
    __shared__ float sp[4];
    const int b = blockIdx.x, d = threadIdx.x;
    const int he = e1[b], hr = rel[b];
    const float ph = emb_e[(size_t)he * 512 + d];
    const float mh = emb_e[(size_t)he * 512 + 256 + d];
    const float pr = emb_rel[(size_t)hr * 768 + d];
    const float mr = emb_rel[(size_t)hr * 768 + 256 + d];
    const float bi = emb_rel[(size_t)hr * 768 + 512 + d];

    const float a = (ph + pr) * K2S;
    PKH x;
    x.h.x = (_Float16)(-cosrev_(a));
    x.h.y = (_Float16)(sinrev_(a));
    ((unsigned*)(ws + WS_XT))[d * 32 + b] = x.u;   // [d][b] for coalesced main loads

    const float mra = fabsf(mr);
    float bic = fminf(bi, 1.0f);
    bic = (bic < -mra) ? -mra : bic;
    const float cc  = 1.0f - bic;
    const float mhp = mh * (mra + bic);
    ((short*)(ws + WS_A1))[b * 256 + d] = (short)bf16r(cc * cc);
    ((short*)(ws + WS_A2))[b * 256 + d] = (short)bf16r(-2.0f * mhp * cc);

    float s0 = mhp * mhp;
#pragma unroll
    for (int o = 1; o < 64; o <<= 1) s0 += __shfl_xor(s0, o, 64);
    if ((threadIdx.x & 63) == 0) sp[threadIdx.x >> 6] = s0;
    __syncthreads();
    if (threadIdx.x == 0)
        ((float*)(ws + WS_S0))[b] = sp[0] + sp[1] + sp[2] + sp[3];
}

// ---------------------------------------------------------------------------
// K1: r-term GEMM (unchanged, proven clean). 313 blocks x 256 thr.
// ---------------------------------------------------------------------------
__global__ __launch_bounds__(256)
void hake_rgemm(const float* __restrict__ emb_e, char* __restrict__ ws)
{
    const int t = threadIdx.x;
    const int w = t >> 6, l = t & 63;
    const int n0 = blockIdx.x * 64 + w * 16;
    if (n0 >= N_) return;                 // wave-uniform guard

    const short* A1w = (const short*)(ws + WS_A1);
    const short* A2w = (const short*)(ws + WS_A2);
    const float* S0w = (const float*)(ws + WS_S0);
    float*       Rw  = (float*)(ws + WS_R);

    const int fr   = l & 15;
    const int koff = (l >> 4) * 8;
    const float* mtp = emb_e + (size_t)(n0 + fr) * (2 * D_) + D_;

    f32x4 acc0 = {0.f, 0.f, 0.f, 0.f};
    f32x4 acc1 = {0.f, 0.f, 0.f, 0.f};
#pragma unroll
    for (int ch = 0; ch < 8; ++ch) {
        const int d = ch * 32 + koff;
        float4 va = *(const float4*)(mtp + d);
        float4 vb = *(const float4*)(mtp + d + 4);
        short8 b2f = pack8(va, vb, false);
        short8 b1f = pack8(va, vb, true);
        short8 a1_0 = *(const short8*)(A1w + fr * 256 + d);
        short8 a2_0 = *(const short8*)(A2w + fr * 256 + d);
        short8 a1_1 = *(const short8*)(A1w + (16 + fr) * 256 + d);
        short8 a2_1 = *(const short8*)(A2w + (16 + fr) * 256 + d);
        acc0 = __builtin_amdgcn_mfma_f32_16x16x32_bf16(a1_0, b1f, acc0, 0, 0, 0);
        acc0 = __builtin_amdgcn_mfma_f32_16x16x32_bf16(a2_0, b2f, acc0, 0, 0, 0);
        acc1 = __builtin_amdgcn_mfma_f32_16x16x32_bf16(a1_1, b1f, acc1, 0, 0, 0);
        acc1 = __builtin_amdgcn_mfma_f32_16x16x32_bf16(a2_1, b2f, acc1, 0, 0, 0);
    }

    // C/D map (verified): col = lane&15 (n), row = (lane>>4)*4 + reg (b)
#pragma unroll
    for (int r = 0; r < 4; ++r) {
        const int row = (l >> 4) * 4 + r;
        Rw[(size_t)row * N_ + n0 + fr]        = acc0[r] + S0w[row];
        Rw[(size_t)(16 + row) * N_ + n0 + fr] = acc1[r] + S0w[16 + row];
    }
}

// ---------------------------------------------------------------------------
// K2: phase + finalize. 2500 blocks x 256 thr, NO min-waves cap.
// X loaded 4-at-a-time inside '#pragma unroll 1' q-loop (L1-hot 32KB table).
// LDS 12.6KB. Live regs ~25-45 -> no spill possible.
// ---------------------------------------------------------------------------
__global__ __launch_bounds__(256)
void hake_main(const float* __restrict__ emb_e,
               const char* __restrict__ ws,
               const float* __restrict__ pw_p, const float* __restrict__ mw_p,
               float* __restrict__ out)
{
    __shared__ unsigned Pb[NT * 256];    // 8 KB packed (sb,cb) half2
    __shared__ float redf[4 * 32 * 9];   // 4.6 KB: [w][b][j] pad 9

    const int t   = threadIdx.x;
    const int l   = t & 63;
    const int w   = t >> 6;       // wave 0..3
    const int b   = t & 31;
    const int g   = t >> 5;       // d-group 0..7 (32 d each)
    const int dlo = g * 32;
    const int n0  = blockIdx.x * NT;

    const unsigned* XTw = (const unsigned*)(ws + WS_XT);
    const float*    Rw  = (const float*)(ws + WS_R);

    // ---- stage Pb: wave w -> rows 2w, 2w+1 (consume lp immediately) --------
    {
        const float* prow0 = emb_e + (size_t)(n0 + w * 2) * (2 * D_);
        const float* prow1 = emb_e + (size_t)(n0 + w * 2 + 1) * (2 * D_);
        float2 lp00 = *(const float2*)(prow0 + 2 * l);
        float2 lp01 = *(const float2*)(prow0 + 128 + 2 * l);
        float2 lp10 = *(const float2*)(prow1 + 2 * l);
        float2 lp11 = *(const float2*)(prow1 + 128 + 2 * l);

        PKH w0, w1;
        float v0, v1;
        v0 = lp00.x * K2S; v1 = lp00.y * K2S;
        w0.h.x = (_Float16)sinrev_(v0); w0.h.y = (_Float16)cosrev_(v0);
        w1.h.x = (_Float16)sinrev_(v1); w1.h.y = (_Float16)cosrev_(v1);
        *(uint2*)(&Pb[(w * 2) * 256 + 2 * l]) = make_uint2(w0.u, w1.u);
        v0 = lp01.x * K2S; v1 = lp01.y * K2S;
        w0.h.x = (_Float16)sinrev_(v0); w0.h.y = (_Float16)cosrev_(v0);
        w1.h.x = (_Float16)sinrev_(v1); w1.h.y = (_Float16)cosrev_(v1);
        *(uint2*)(&Pb[(w * 2) * 256 + 128 + 2 * l]) = make_uint2(w0.u, w1.u);
        v0 = lp10.x * K2S; v1 = lp10.y * K2S;
        w0.h.x = (_Float16)sinrev_(v0); w0.h.y = (_Float16)cosrev_(v0);
        w1.h.x = (_Float16)sinrev_(v1); w1.h.y = (_Float16)cosrev_(v1);
        *(uint2*)(&Pb[(w * 2 + 1) * 256 + 2 * l]) = make_uint2(w0.u, w1.u);
        v0 = lp11.x * K2S; v1 = lp11.y * K2S;
        w0.h.x = (_Float16)sinrev_(v0); w0.h.y = (_Float16)cosrev_(v0);
        w1.h.x = (_Float16)sinrev_(v1); w1.h.y = (_Float16)cosrev_(v1);
        *(uint2*)(&Pb[(w * 2 + 1) * 256 + 128 + 2 * l]) = make_uint2(w0.u, w1.u);
    }

    __syncthreads();                                    // b1: Pb ready

    // ---- R prefetch (latency hides under inner loop) -----------------------
    const int fn = t & 7, fb = t >> 3;
    const float rpre = Rw[(size_t)fb * N_ + n0 + fn];

    // ---- phase accumulate: q-loop kept as a REAL loop (unroll 1) -----------
    float sph[NT];
#pragma unroll
    for (int j = 0; j < NT; ++j) sph[j] = 0.0f;

    const unsigned* xb = XTw + (size_t)dlo * 32 + b;    // X base for this thread
#pragma unroll 1
    for (int q = 0; q < 8; ++q) {
        // 4 X dwords for d = dlo+4q .. dlo+4q+3 (L1-hot, coalesced per group)
        const half2_t x0 = __builtin_bit_cast(half2_t, xb[(q * 4 + 0) * 32]);
        const half2_t x1 = __builtin_bit_cast(half2_t, xb[(q * 4 + 1) * 32]);
        const half2_t x2 = __builtin_bit_cast(half2_t, xb[(q * 4 + 2) * 32]);
        const half2_t x3 = __builtin_bit_cast(half2_t, xb[(q * 4 + 3) * 32]);
#pragma unroll
        for (int j = 0; j < NT; ++j) {
            uint4 tv = *(const uint4*)(&Pb[j * 256 + dlo + q * 4]);   // bcast
            sph[j] += fabsf(__builtin_amdgcn_fdot2(x0, __builtin_bit_cast(half2_t, tv.x), 0.0f, false));
            sph[j] += fabsf(__builtin_amdgcn_fdot2(x1, __builtin_bit_cast(half2_t, tv.y), 0.0f, false));
            sph[j] += fabsf(__builtin_amdgcn_fdot2(x2, __builtin_bit_cast(half2_t, tv.z), 0.0f, false));
            sph[j] += fabsf(__builtin_amdgcn_fdot2(x3, __builtin_bit_cast(half2_t, tv.w), 0.0f, false));
        }
    }

    // ---- reduce: half-wave combine, scalar writes [w][b=l][j] --------------
#pragma unroll
    for (int j = 0; j < NT; ++j) sph[j] += __shfl_xor(sph[j], 32, 64);
    if (l < 32) {
#pragma unroll
        for (int j = 0; j < NT; ++j) redf[(w * 32 + l) * 9 + j] = sph[j];
    }
    __syncthreads();                                    // b2: redf ready

    // ---- finalize: thread -> (b = t>>3, n = n0 + (t&7)) --------------------
    {
        float pa = 0.0f;
#pragma unroll
        for (int ww = 0; ww < 4; ++ww) pa += redf[(ww * 32 + fb) * 9 + fn];
        float rfull = fmaxf(rpre, 0.0f);
        float z = fmaf(pa, pw_p[0], sqrtf(rfull) * mw_p[0]) - 12.0f;  // GAMMA
        out[(size_t)fb * N_ + (n0 + fn)] = 1.0f / (1.0f + __expf(z));
    }
}

extern "C" void kernel_launch(void* const* d_in, const int* in_sizes, int n_in,
                              void* d_out, int out_size, void* d_ws, size_t ws_size,
                              hipStream_t stream)
{
    // inputs: 0:g 1:e1 2:rel 3:e2_multi(unused) 4:emb_e 5:emb_rel 6:phase_w 7:mod_w
    const int*   e1      = (const int*)d_in[1];
    const int*   rel     = (const int*)d_in[2];
    const float* emb_e   = (const float*)d_in[4];
    const float* emb_rel = (const float*)d_in[5];
    const float* pw      = (const float*)d_in[6];
    const float* mw      = (const float*)d_in[7];
    float* out = (float*)d_out;

    hipLaunchKernelGGL(hake_prep, dim3(32), dim3(256), 0, stream,
                       e1, rel, emb_e, emb_rel, (char*)d_ws);
    hipLaunchKernelGGL(hake_rgemm, dim3(313), dim3(256), 0, stream,
                       emb_e, (char*)d_ws);
    hipLaunchKernelGGL(hake_main, dim3(NBLK), dim3(256), 0, stream,
                       emb_e, (const char*)d_ws, pw, mw, out);
}

// Round 17
// 43.699 us; speedup vs baseline: 2.6754x; 1.0277x over previous
//
#include <hip/hip_runtime.h>
#include <math.h>

// HAKE scoring for MI355X — round 17: fine-grained barrier domains.
// Ledger: phase wall (~26-30us) invariant under VALU count, LDS instr count,
// occupancy%, gathers. Untested variable: barrier-domain granularity — all
// fused variants used 512-thr blocks at <=4 blocks/CU (barrier stalls all 8
// waves, 3 fillers). Now: 256-thr blocks, NT=8, grid 2500, 16.9KB LDS,
// ~56 VGPR -> ~8 blocks/CU. MFMA r-term fused (4 waves x (term,128k), 16-col
// tile, cols 8-15 clamped/discarded). Spill discipline: unroll-1 loops,
// in-loop X/B loads, no min-waves cap.

#define D_   256
#define N_   20000
#define NT   8
#define NBLK (N_ / NT)      // 2500

// rev units for sin(x/2): 1/(4*EMB_RANGE)
#define K2S 4.571428571428571f

// ws layout (bytes)
#define WS_A1 0          // 32x256 bf16
#define WS_A2 16384      // 32x256 bf16
#define WS_XT 32768      // 256x32 u32 (packed half2 (-cos,sin)), [d][b]
#define WS_S0 65536      // 32 f32

typedef short short8 __attribute__((ext_vector_type(8)));
typedef float f32x4  __attribute__((ext_vector_type(4)));
typedef _Float16 half2_t __attribute__((ext_vector_type(2)));

union PKH { unsigned u; half2_t h; };

__device__ __forceinline__ float sinrev_(float x) { return __builtin_amdgcn_sinf(x); }
__device__ __forceinline__ float cosrev_(float x) { return __builtin_amdgcn_cosf(x); }

__device__ __forceinline__ unsigned short bf16r(float x) {
    union { float f; unsigned u; } v; v.f = x;
    return (unsigned short)((v.u + 0x7FFFu + ((v.u >> 16) & 1u)) >> 16);
}

__device__ __forceinline__ short8 pack8(float4 a, float4 b, bool sq) {
    float v[8] = {a.x, a.y, a.z, a.w, b.x, b.y, b.z, b.w};
    short8 r;
#pragma unroll
    for (int i = 0; i < 8; ++i) { float x = sq ? v[i] * v[i] : v[i]; r[i] = (short)bf16r(x); }
    return r;
}

// ---------------------------------------------------------------------------
// K0: per-(b,d) precompute. 32 blocks x 256 thr. (unchanged, proven clean)
// A1=cc^2, A2=-2mh'cc (bf16 [b][d]); XT = packed half2 (-cos,sin) [d][b];
// S0[b] = sum mh'^2.
// ---------------------------------------------------------------------------
__global__ __launch_bounds__(256)
void hake_prep(const int* __restrict__ e1, const int* __restrict__ rel,
               const float* __restrict__ emb_e, const float* __restrict__ emb_rel,
               char* __restrict__ ws)
{
    __shared__ float sp[4];
    const int b = blockIdx.x, d = threadIdx.x;
    const int he = e1[b], hr = rel[b];
    const float ph = emb_e[(size_t)he * 512 + d];
    const float mh = emb_e[(size_t)he * 512 + 256 + d];
    const float pr = emb_rel[(size_t)hr * 768 + d];
    const float mr = emb_rel[(size_t)hr * 768 + 256 + d];
    const float bi = emb_rel[(size_t)hr * 768 + 512 + d];

    const float a = (ph + pr) * K2S;
    PKH x;
    x.h.x = (_Float16)(-cosrev_(a));
    x.h.y = (_Float16)(sinrev_(a));
    ((unsigned*)(ws + WS_XT))[d * 32 + b] = x.u;

    const float mra = fabsf(mr);
    float bic = fminf(bi, 1.0f);
    bic = (bic < -mra) ? -mra : bic;
    const float cc  = 1.0f - bic;
    const float mhp = mh * (mra + bic);
    ((short*)(ws + WS_A1))[b * 256 + d] = (short)bf16r(cc * cc);
    ((short*)(ws + WS_A2))[b * 256 + d] = (short)bf16r(-2.0f * mhp * cc);

    float s0 = mhp * mhp;
#pragma unroll
    for (int o = 1; o < 64; o <<= 1) s0 += __shfl_xor(s0, o, 64);
    if ((threadIdx.x & 63) == 0) sp[threadIdx.x >> 6] = s0;
    __syncthreads();
    if (threadIdx.x == 0)
        ((float*)(ws + WS_S0))[b] = sp[0] + sp[1] + sp[2] + sp[3];
}

// ---------------------------------------------------------------------------
// Main: 2500 blocks x 256 thr (4 waves), NT=8 rows. LDS 16.9KB -> ~8 blk/CU.
// Wave w: stages 2 phase rows; MFMA slice (term=w>>1, kbase=(w&1)*128).
// Phase: thread owns (b=t&31, 32 d), dot2 inner, unroll-1 q-loop.
// ---------------------------------------------------------------------------
__global__ __launch_bounds__(256)
void hake_main(const float* __restrict__ emb_e,
               const char* __restrict__ ws,
               const float* __restrict__ pw_p, const float* __restrict__ mw_p,
               float* __restrict__ out)
{
    __shared__ unsigned Pb[NT * 256];      // 8 KB packed (sb,cb) half2; reused as redf
    __shared__ float redr[4][32][17];      // 8.7 KB MFMA partials

    const int t   = threadIdx.x;
    const int l   = t & 63;
    const int w   = t >> 6;       // wave 0..3
    const int b   = t & 31;
    const int g   = t >> 5;       // d-group 0..7 (32 d each)
    const int dlo = g * 32;
    const int n0  = blockIdx.x * NT;

    const short*    A1w = (const short*)(ws + WS_A1);
    const short*    A2w = (const short*)(ws + WS_A2);
    const unsigned* XTw = (const unsigned*)(ws + WS_XT);
    const float*    S0w = (const float*)(ws + WS_S0);

    // ---- stage Pb: wave w -> rows 2w, 2w+1 (consume lp immediately) --------
    {
        const float* prow0 = emb_e + (size_t)(n0 + w * 2) * (2 * D_);
        const float* prow1 = emb_e + (size_t)(n0 + w * 2 + 1) * (2 * D_);
        float2 lp00 = *(const float2*)(prow0 + 2 * l);
        float2 lp01 = *(const float2*)(prow0 + 128 + 2 * l);
        float2 lp10 = *(const float2*)(prow1 + 2 * l);
        float2 lp11 = *(const float2*)(prow1 + 128 + 2 * l);

        PKH w0, w1;
        float v0, v1;
        v0 = lp00.x * K2S; v1 = lp00.y * K2S;
        w0.h.x = (_Float16)sinrev_(v0); w0.h.y = (_Float16)cosrev_(v0);
        w1.h.x = (_Float16)sinrev_(v1); w1.h.y = (_Float16)cosrev_(v1);
        *(uint2*)(&Pb[(w * 2) * 256 + 2 * l]) = make_uint2(w0.u, w1.u);
        v0 = lp01.x * K2S; v1 = lp01.y * K2S;
        w0.h.x = (_Float16)sinrev_(v0); w0.h.y = (_Float16)cosrev_(v0);
        w1.h.x = (_Float16)sinrev_(v1); w1.h.y = (_Float16)cosrev_(v1);
        *(uint2*)(&Pb[(w * 2) * 256 + 128 + 2 * l]) = make_uint2(w0.u, w1.u);
        v0 = lp10.x * K2S; v1 = lp10.y * K2S;
        w0.h.x = (_Float16)sinrev_(v0); w0.h.y = (_Float16)cosrev_(v0);
        w1.h.x = (_Float16)sinrev_(v1); w1.h.y = (_Float16)cosrev_(v1);
        *(uint2*)(&Pb[(w * 2 + 1) * 256 + 2 * l]) = make_uint2(w0.u, w1.u);
        v0 = lp11.x * K2S; v1 = lp11.y * K2S;
        w0.h.x = (_Float16)sinrev_(v0); w0.h.y = (_Float16)cosrev_(v0);
        w1.h.x = (_Float16)sinrev_(v1); w1.h.y = (_Float16)cosrev_(v1);
        *(uint2*)(&Pb[(w * 2 + 1) * 256 + 128 + 2 * l]) = make_uint2(w0.u, w1.u);
    }

    // ---- fused r-term MFMA: wave w -> (term = w>>1, kbase = (w&1)*128) -----
    {
        const int fr   = l & 15;
        const int hi2  = l >> 4;           // k-subgroup 0..3
        const int term = w >> 1;
        const int kb   = (w & 1) * 128;
        const short* At = term ? A2w : A1w;
        // B rows: block owns 8 n-rows; cols 8-15 clamped (outputs discarded)
        const float* mtp = emb_e + (size_t)(n0 + (fr & 7)) * (2 * D_) + D_;

        f32x4 acc0 = {0.f, 0.f, 0.f, 0.f};
        f32x4 acc1 = {0.f, 0.f, 0.f, 0.f};
#pragma unroll 1
        for (int ch = 0; ch < 4; ++ch) {
            const int d = kb + ch * 32 + hi2 * 8;
            float4 va = *(const float4*)(mtp + d);
            float4 vb = *(const float4*)(mtp + d + 4);
            short8 bf = pack8(va, vb, term == 0);     // term0: mt^2, term1: mt
            short8 a0 = *(const short8*)(At + fr * 256 + d);
            short8 a1 = *(const short8*)(At + (16 + fr) * 256 + d);
            acc0 = __builtin_amdgcn_mfma_f32_16x16x32_bf16(a0, bf, acc0, 0, 0, 0);
            acc1 = __builtin_amdgcn_mfma_f32_16x16x32_bf16(a1, bf, acc1, 0, 0, 0);
        }
        // C/D map (verified): col = lane&15 (n), row = (lane>>4)*4 + reg (b)
#pragma unroll
        for (int r = 0; r < 4; ++r) {
            redr[w][hi2 * 4 + r][fr]      = acc0[r];
            redr[w][16 + hi2 * 4 + r][fr] = acc1[r];
        }
    }
    __syncthreads();                                    // b1: Pb + redr ready

    // ---- r reduce: thread -> (fb = t>>3, fn = t&7) -------------------------
    const int fn = t & 7, fb = t >> 3;
    float rr = redr[0][fb][fn] + redr[1][fb][fn] + redr[2][fb][fn] + redr[3][fb][fn];

    // ---- phase accumulate: unroll-1 q-loop, in-loop X loads (no spill) -----
    float sph[NT];
#pragma unroll
    for (int j = 0; j < NT; ++j) sph[j] = 0.0f;

    const unsigned* xb = XTw + (size_t)dlo * 32 + b;
#pragma unroll 1
    for (int q = 0; q < 8; ++q) {
        const half2_t x0 = __builtin_bit_cast(half2_t, xb[(q * 4 + 0) * 32]);
        const half2_t x1 = __builtin_bit_cast(half2_t, xb[(q * 4 + 1) * 32]);
        const half2_t x2 = __builtin_bit_cast(half2_t, xb[(q * 4 + 2) * 32]);
        const half2_t x3 = __builtin_bit_cast(half2_t, xb[(q * 4 + 3) * 32]);
#pragma unroll
        for (int j = 0; j < NT; ++j) {
            uint4 tv = *(const uint4*)(&Pb[j * 256 + dlo + q * 4]);   // bcast
            sph[j] += fabsf(__builtin_amdgcn_fdot2(x0, __builtin_bit_cast(half2_t, tv.x), 0.0f, false));
            sph[j] += fabsf(__builtin_amdgcn_fdot2(x1, __builtin_bit_cast(half2_t, tv.y), 0.0f, false));
            sph[j] += fabsf(__builtin_amdgcn_fdot2(x2, __builtin_bit_cast(half2_t, tv.z), 0.0f, false));
            sph[j] += fabsf(__builtin_amdgcn_fdot2(x3, __builtin_bit_cast(half2_t, tv.w), 0.0f, false));
        }
    }

    // ---- phase reduce: shfl combine, redf reuses Pb region -----------------
#pragma unroll
    for (int j = 0; j < NT; ++j) sph[j] += __shfl_xor(sph[j], 32, 64);
    __syncthreads();                                    // b2: Pb + redr consumed
    float* redf = (float*)Pb;                           // [4][32][9] pad
    if (l < 32) {
#pragma unroll
        for (int j = 0; j < NT; ++j) redf[(w * 32 + l) * 9 + j] = sph[j];
    }
    __syncthreads();                                    // b3: redf ready

    // ---- finalize: thread -> (b = fb, n = n0 + fn) -------------------------
    {
        float pa = 0.0f;
#pragma unroll
        for (int ww = 0; ww < 4; ++ww) pa += redf[(ww * 32 + fb) * 9 + fn];
        float rfull = fmaxf(rr + S0w[fb], 0.0f);
        float z = fmaf(pa, pw_p[0], sqrtf(rfull) * mw_p[0]) - 12.0f;  // GAMMA
        out[(size_t)fb * N_ + (n0 + fn)] = 1.0f / (1.0f + __expf(z));
    }
}

extern "C" void kernel_launch(void* const* d_in, const int* in_sizes, int n_in,
                              void* d_out, int out_size, void* d_ws, size_t ws_size,
                              hipStream_t stream)
{
    // inputs: 0:g 1:e1 2:rel 3:e2_multi(unused) 4:emb_e 5:emb_rel 6:phase_w 7:mod_w
    const int*   e1      = (const int*)d_in[1];
    const int*   rel     = (const int*)d_in[2];
    const float* emb_e   = (const float*)d_in[4];
    const float* emb_rel = (const float*)d_in[5];
    const float* pw      = (const float*)d_in[6];
    const float* mw      = (const float*)d_in[7];
    float* out = (float*)d_out;

    hipLaunchKernelGGL(hake_prep, dim3(32), dim3(256), 0, stream,
                       e1, rel, emb_e, emb_rel, (char*)d_ws);
    hipLaunchKernelGGL(hake_main, dim3(NBLK), dim3(256), 0, stream,
                       emb_e, (const char*)d_ws, pw, mw, out);
}

// Round 18
// 38.725 us; speedup vs baseline: 3.0190x; 1.1284x over previous
//
#include <hip/hip_runtime.h>
#include <math.h>

// HAKE scoring for MI355X — round 18: outer-product register tiling.
// Ledger: R10-structure wall (~28us main) = LDS-pipe + VALU as a SUM; the
// broadcast ds_read_b128 feeds only 4 triples/12cyc. Fix: lane owns 4b x 4j
// acc tile; per d: one uint4 X (GLOBAL, L1-hot 32KB - off the LDS pipe) +
// one uint4 P from transposed padded Pt[d][17] (conflict-free, 8 distinct
// lines/instr) -> 16 triples per read-pair; LDS reads/wave 64 -> 16.
// Keep R10 envelope: NT=16, 512thr, grid 1250, fused MFMA r-term, prep.
// Spill discipline: unroll-1 d-loop, always-live acc, no min-waves cap.

#define D_   256
#define N_   20000
#define NT   16
#define NBLK (N_ / NT)      // 1250

// rev units for sin(x/2): 1/(4*EMB_RANGE)
#define K2S 4.571428571428571f

// ws layout (bytes)
#define WS_A1 0          // 32x256 bf16
#define WS_A2 16384      // 32x256 bf16
#define WS_XT 32768      // 256x32 u32 (packed half2 (-cos,sin)), [d][b]
#define WS_S0 65536      // 32 f32

typedef short short8 __attribute__((ext_vector_type(8)));
typedef float f32x4  __attribute__((ext_vector_type(4)));
typedef _Float16 half2_t __attribute__((ext_vector_type(2)));

union PKH { unsigned u; half2_t h; };

__device__ __forceinline__ float sinrev_(float x) { return __builtin_amdgcn_sinf(x); }
__device__ __forceinline__ float cosrev_(float x) { return __builtin_amdgcn_cosf(x); }
__device__ __forceinline__ half2_t h2_(unsigned u) { return __builtin_bit_cast(half2_t, u); }

__device__ __forceinline__ unsigned short bf16r(float x) {
    union { float f; unsigned u; } v; v.f = x;
    return (unsigned short)((v.u + 0x7FFFu + ((v.u >> 16) & 1u)) >> 16);
}

__device__ __forceinline__ short8 pack8(float4 a, float4 b, bool sq) {
    float v[8] = {a.x, a.y, a.z, a.w, b.x, b.y, b.z, b.w};
    short8 r;
#pragma unroll
    for (int i = 0; i < 8; ++i) { float x = sq ? v[i] * v[i] : v[i]; r[i] = (short)bf16r(x); }
    return r;
}

__device__ __forceinline__ unsigned packsc_(float v) {
    PKH p; p.h.x = (_Float16)sinrev_(v); p.h.y = (_Float16)cosrev_(v);
    return p.u;
}

// ---------------------------------------------------------------------------
// K0: per-(b,d) precompute. 32 blocks x 256 thr. (unchanged, proven clean)
// ---------------------------------------------------------------------------
__global__ __launch_bounds__(256)
void hake_prep(const int* __restrict__ e1, const int* __restrict__ rel,
               const float* __restrict__ emb_e, const float* __restrict__ emb_rel,
               char* __restrict__ ws)
{
    __shared__ float sp[4];
    const int b = blockIdx.x, d = threadIdx.x;
    const int he = e1[b], hr = rel[b];
    const float ph = emb_e[(size_t)he * 512 + d];
    const float mh = emb_e[(size_t)he * 512 + 256 + d];
    const float pr = emb_rel[(size_t)hr * 768 + d];
    const float mr = emb_rel[(size_t)hr * 768 + 256 + d];
    const float bi = emb_rel[(size_t)hr * 768 + 512 + d];

    const float a = (ph + pr) * K2S;
    PKH x;
    x.h.x = (_Float16)(-cosrev_(a));
    x.h.y = (_Float16)(sinrev_(a));
    ((unsigned*)(ws + WS_XT))[d * 32 + b] = x.u;   // [d][b]

    const float mra = fabsf(mr);
    float bic = fminf(bi, 1.0f);
    bic = (bic < -mra) ? -mra : bic;
    const float cc  = 1.0f - bic;
    const float mhp = mh * (mra + bic);
    ((short*)(ws + WS_A1))[b * 256 + d] = (short)bf16r(cc * cc);
    ((short*)(ws + WS_A2))[b * 256 + d] = (short)bf16r(-2.0f * mhp * cc);

    float s0 = mhp * mhp;
#pragma unroll
    for (int o = 1; o < 64; o <<= 1) s0 += __shfl_xor(s0, o, 64);
    if ((threadIdx.x & 63) == 0) sp[threadIdx.x >> 6] = s0;
    __syncthreads();
    if (threadIdx.x == 0)
        ((float*)(ws + WS_S0))[b] = sp[0] + sp[1] + sp[2] + sp[3];
}

// ---------------------------------------------------------------------------
// Main: 1250 blocks x 512 thr. Pt[d][17] transposed packed P; U = MFMA
// partials then phase-reduce buffer. Outer-product phase inner loop.
// ---------------------------------------------------------------------------
__global__ __launch_bounds__(512)
void hake_main(const float* __restrict__ emb_e,
               const char* __restrict__ ws,
               const float* __restrict__ pw_p, const float* __restrict__ mw_p,
               float* __restrict__ out)
{
    __shared__ unsigned Pt[256 * 17];    // 17.4 KB: [d][j] padded (16 j + 1)
    __shared__ float U[8 * 32 * 17];     // 17.4 KB: MFMA partials | redf

    const int t   = threadIdx.x;
    const int l   = t & 63;
    const int w   = t >> 6;       // wave 0..7
    const int g   = t >> 5;       // d-group 0..15 (16 d each)
    const int lg  = t & 31;
    const int bq  = lg >> 2;      // b-quad 0..7
    const int jq  = lg & 3;       // j-quad 0..3
    const int dlo = g * 16;
    const int n0  = blockIdx.x * NT;

    const short*    A1w = (const short*)(ws + WS_A1);
    const short*    A2w = (const short*)(ws + WS_A2);
    const unsigned* XTw = (const unsigned*)(ws + WS_XT);
    const float*    S0w = (const float*)(ws + WS_S0);

    // ---- B-frag loads for MFMA (R10 pattern) -------------------------------
    const int term  = w >> 2;
    const int dbase = (w & 3) * 64;
    const int fr    = l & 15;
    const int hi    = l >> 4;
    const float* mtp = emb_e + (size_t)(n0 + fr) * (2 * D_) + D_;
    float4 bva0 = *(const float4*)(mtp + dbase + hi * 8);
    float4 bvb0 = *(const float4*)(mtp + dbase + hi * 8 + 4);
    float4 bva1 = *(const float4*)(mtp + dbase + 32 + hi * 8);
    float4 bvb1 = *(const float4*)(mtp + dbase + 32 + hi * 8 + 4);

    // ---- stage Pt (transposed): wave w -> rows 2w, 2w+1 --------------------
    {
        const int j0 = w * 2;
        const float* prow0 = emb_e + (size_t)(n0 + j0) * (2 * D_);
        const float* prow1 = emb_e + (size_t)(n0 + j0 + 1) * (2 * D_);
        float2 lp00 = *(const float2*)(prow0 + 2 * l);
        float2 lp01 = *(const float2*)(prow0 + 128 + 2 * l);
        float2 lp10 = *(const float2*)(prow1 + 2 * l);
        float2 lp11 = *(const float2*)(prow1 + 128 + 2 * l);

        Pt[(2 * l) * 17 + j0]           = packsc_(lp00.x * K2S);
        Pt[(2 * l + 1) * 17 + j0]       = packsc_(lp00.y * K2S);
        Pt[(128 + 2 * l) * 17 + j0]     = packsc_(lp01.x * K2S);
        Pt[(128 + 2 * l + 1) * 17 + j0] = packsc_(lp01.y * K2S);
        Pt[(2 * l) * 17 + j0 + 1]           = packsc_(lp10.x * K2S);
        Pt[(2 * l + 1) * 17 + j0 + 1]       = packsc_(lp10.y * K2S);
        Pt[(128 + 2 * l) * 17 + j0 + 1]     = packsc_(lp11.x * K2S);
        Pt[(128 + 2 * l + 1) * 17 + j0 + 1] = packsc_(lp11.y * K2S);
    }

    // ---- fused r-term MFMA (R10 exact) -------------------------------------
    {
        const short* At = term ? A2w : A1w;
        short8 bf0 = pack8(bva0, bvb0, term == 0);
        short8 bf1 = pack8(bva1, bvb1, term == 0);
        short8 a00 = *(const short8*)(At + fr * 256 + dbase + hi * 8);
        short8 a01 = *(const short8*)(At + fr * 256 + dbase + 32 + hi * 8);
        short8 a10 = *(const short8*)(At + (16 + fr) * 256 + dbase + hi * 8);
        short8 a11 = *(const short8*)(At + (16 + fr) * 256 + dbase + 32 + hi * 8);
        f32x4 acc0 = {0.f, 0.f, 0.f, 0.f};
        f32x4 acc1 = {0.f, 0.f, 0.f, 0.f};
        acc0 = __builtin_amdgcn_mfma_f32_16x16x32_bf16(a00, bf0, acc0, 0, 0, 0);
        acc0 = __builtin_amdgcn_mfma_f32_16x16x32_bf16(a01, bf1, acc0, 0, 0, 0);
        acc1 = __builtin_amdgcn_mfma_f32_16x16x32_bf16(a10, bf0, acc1, 0, 0, 0);
        acc1 = __builtin_amdgcn_mfma_f32_16x16x32_bf16(a11, bf1, acc1, 0, 0, 0);
        // C/D map (verified): col = lane&15 (n), row = hi*4 + reg (b)
#pragma unroll
        for (int r = 0; r < 4; ++r) {
            U[(w * 32 + hi * 4 + r) * 17 + fr]      = acc0[r];
            U[(w * 32 + 16 + hi * 4 + r) * 17 + fr] = acc1[r];
        }
    }
    __syncthreads();                                    // b1: Pt + U ready

    // ---- r reduce: thread -> (fb = t>>4 [b], fn = t&15 [n]) ----------------
    const int fn = t & 15, fb = t >> 4;
    float rr = 0.0f;
#pragma unroll
    for (int ww = 0; ww < 8; ++ww) rr += U[(ww * 32 + fb) * 17 + fn];

    // ---- phase: outer-product 4b x 4j tile, unroll-1 d-loop ----------------
    float acc[4][4];
#pragma unroll
    for (int bi = 0; bi < 4; ++bi)
#pragma unroll
        for (int ji = 0; ji < 4; ++ji) acc[bi][ji] = 0.0f;

#pragma unroll 1
    for (int dd = 0; dd < 16; ++dd) {
        const int d = dlo + dd;
        uint4 xv = *(const uint4*)(XTw + d * 32 + bq * 4);    // 4 b's (global L1)
        uint4 pv = *(const uint4*)(&Pt[d * 17 + jq * 4]);     // 4 j's (LDS)
        const unsigned xs[4] = {xv.x, xv.y, xv.z, xv.w};
        const unsigned ps[4] = {pv.x, pv.y, pv.z, pv.w};
#pragma unroll
        for (int bi = 0; bi < 4; ++bi) {
#pragma unroll
            for (int ji = 0; ji < 4; ++ji) {
                acc[bi][ji] += fabsf(__builtin_amdgcn_fdot2(h2_(xs[bi]), h2_(ps[ji]), 0.0f, false));
            }
        }
    }

    // ---- combine g-pairs, then cross-wave via U ----------------------------
#pragma unroll
    for (int bi = 0; bi < 4; ++bi)
#pragma unroll
        for (int ji = 0; ji < 4; ++ji)
            acc[bi][ji] += __shfl_xor(acc[bi][ji], 32, 64);
    __syncthreads();                                    // b2: U consumed (rr read)
    if (l < 32) {
#pragma unroll
        for (int bi = 0; bi < 4; ++bi)
#pragma unroll
            for (int ji = 0; ji < 4; ++ji)
                U[(w * 32 + lg) * 17 + bi * 4 + ji] = acc[bi][ji];
    }
    __syncthreads();                                    // b3: redf ready

    // ---- finalize: thread -> (b = fb, j = fn) ------------------------------
    {
        const int lgk = (fb >> 2) * 4 + (fn >> 2);      // bq*4 + jq
        const int k   = (fb & 3) * 4 + (fn & 3);        // bi*4 + ji
        float pa = 0.0f;
#pragma unroll
        for (int ww = 0; ww < 8; ++ww) pa += U[(ww * 32 + lgk) * 17 + k];
        float rfull = fmaxf(rr + S0w[fb], 0.0f);
        float z = fmaf(pa, pw_p[0], sqrtf(rfull) * mw_p[0]) - 12.0f;  // GAMMA
        out[(size_t)fb * N_ + (n0 + fn)] = 1.0f / (1.0f + __expf(z));
    }
}

extern "C" void kernel_launch(void* const* d_in, const int* in_sizes, int n_in,
                              void* d_out, int out_size, void* d_ws, size_t ws_size,
                              hipStream_t stream)
{
    // inputs: 0:g 1:e1 2:rel 3:e2_multi(unused) 4:emb_e 5:emb_rel 6:phase_w 7:mod_w
    const int*   e1      = (const int*)d_in[1];
    const int*   rel     = (const int*)d_in[2];
    const float* emb_e   = (const float*)d_in[4];
    const float* emb_rel = (const float*)d_in[5];
    const float* pw      = (const float*)d_in[6];
    const float* mw      = (const float*)d_in[7];
    float* out = (float*)d_out;

    hipLaunchKernelGGL(hake_prep, dim3(32), dim3(256), 0, stream,
                       e1, rel, emb_e, emb_rel, (char*)d_ws);
    hipLaunchKernelGGL(hake_main, dim3(NBLK), dim3(512), 0, stream,
                       emb_e, (const char*)d_ws, pw, mw, out);
}